// Round 11
// baseline (280.356 us; speedup 1.0000x reference)
//
#include <hip/hip_runtime.h>
#include <cstdint>

typedef __bf16 bf16_t;
typedef __attribute__((ext_vector_type(2))) __bf16 bf16x2;
typedef __attribute__((ext_vector_type(4))) __bf16 bf16x4;
typedef __attribute__((ext_vector_type(8))) __bf16 bf16x8;
typedef __attribute__((ext_vector_type(4))) float f32x4;
typedef __attribute__((ext_vector_type(16))) float f32x16;
typedef __attribute__((ext_vector_type(4))) int i32x4;

constexpr int Bx = 2, Nx = 2048, MEMx = 2048, Jx = 4096, DIMx = 1024, Hx = 16, HDx = 64;

__device__ __forceinline__ void gload_lds16(const bf16_t* g, bf16_t* lds) {
  __builtin_amdgcn_global_load_lds(
      (const __attribute__((address_space(1))) unsigned int*)g,
      (__attribute__((address_space(3))) unsigned int*)lds, 16, 0, 0);
}

__device__ __forceinline__ int pk2(float a, float b) {
  bf16x2 t;
  t[0] = (bf16_t)a;
  t[1] = (bf16_t)b;
  return __builtin_bit_cast(int, t);
}

__device__ __forceinline__ void pl32swap(int& a, int& b) {
  asm volatile("v_permlane32_swap_b32 %0, %1" : "+v"(a), "+v"(b));
}

__device__ __forceinline__ float fmax3(float a, float b, float c) {
  float d;
  asm("v_max3_f32 %0, %1, %2, %3" : "=v"(d) : "v"(a), "v"(b), "v"(c));
  return d;
}

// ---------------- convert / pack (vectorized) ----------------
__global__ void k_build8(const float* __restrict__ x, const float* __restrict__ mem,
                         bf16_t* __restrict__ xb, bf16_t* __restrict__ ctxb) {
  const int XT8 = (Bx * Nx * DIMx) >> 3;
  const int CT8 = (Bx * Jx * DIMx) >> 3;
  for (int i = blockIdx.x * blockDim.x + threadIdx.x; i < XT8 + CT8;
       i += gridDim.x * blockDim.x) {
    const float* src;
    bf16_t* dst;
    if (i < XT8) {
      src = x + ((int64_t)i << 3);
      dst = xb + ((int64_t)i << 3);
    } else {
      int64_t c = (int64_t)(i - XT8) << 3;
      int bb = (int)(c >> 22);
      int rr = (int)(c & ((1 << 22) - 1));
      int j = rr >> 10, d = rr & 1023;
      src = (j < MEMx) ? mem + (((int64_t)(bb * MEMx + j)) << 10) + d
                       : x + (((int64_t)(bb * Nx + (j - MEMx))) << 10) + d;
      dst = ctxb + c;
    }
    float4 a = *(const float4*)src;
    float4 b = *(const float4*)(src + 4);
    bf16x8 v;
    v[0] = (bf16_t)a.x; v[1] = (bf16_t)a.y; v[2] = (bf16_t)a.z; v[3] = (bf16_t)a.w;
    v[4] = (bf16_t)b.x; v[5] = (bf16_t)b.y; v[6] = (bf16_t)b.z; v[7] = (bf16_t)b.w;
    *(bf16x8*)dst = v;
  }
}

__global__ void k_transpose_tiled(const float* __restrict__ W, bf16_t* __restrict__ WT,
                                  int K, int Nc) {
  __shared__ bf16_t t[32][33];
  const int tx = threadIdx.x & 31, ty = threadIdx.x >> 5;
  const int n0 = blockIdx.x * 32, k0 = blockIdx.y * 32;
#pragma unroll
  for (int r = 0; r < 4; ++r)
    t[ty + 8 * r][tx] = (bf16_t)W[(int64_t)(k0 + ty + 8 * r) * Nc + n0 + tx];
  __syncthreads();
#pragma unroll
  for (int r = 0; r < 4; ++r)
    WT[(int64_t)(n0 + ty + 8 * r) * K + k0 + tx] = t[tx][ty + 8 * r];
}

// ---------------- GEMM (depth-2 counted-vmcnt) ----------------
template <int MODE>
__launch_bounds__(256)
__global__ void k_gemm_bt(const bf16_t* __restrict__ A, const bf16_t* __restrict__ BT,
                          void* __restrict__ Cv, const float* __restrict__ bias,
                          const float* __restrict__ gate, bf16_t* __restrict__ VT,
                          float scale, int M, int Nc, int K) {
  __shared__ bf16_t As[2][128 * 32];
  __shared__ bf16_t Bs[2][128 * 32];
  const int tid = threadIdx.x;
  const int w = tid >> 6, l = tid & 63;
  const int lr = l & 15, lg = l >> 4;
  const int m0 = blockIdx.y * 128, n0 = blockIdx.x * 128;
  const int wm = (w >> 1) * 64, wn = (w & 1) * 64;

  const int srow = w * 16 + (l >> 2);
  const int scol = (l & 3) * 8;
  const bf16_t* ga0 = A + (int64_t)(m0 + srow) * K + scol;
  const bf16_t* gb0 = BT + (int64_t)(n0 + srow) * K + scol;

  auto stage = [&](int bufi, int k0) {
    bf16_t* lA = &As[bufi][0] + w * 512;
    bf16_t* lB = &Bs[bufi][0] + w * 512;
    gload_lds16(ga0 + k0, lA);
    gload_lds16(ga0 + (int64_t)64 * K + k0, lA + 2048);
    gload_lds16(gb0 + k0, lB);
    gload_lds16(gb0 + (int64_t)64 * K + k0, lB + 2048);
  };

  f32x4 acc[4][4] = {};

  const int nsteps = K >> 5;
  stage(0, 0);
  stage(1, 32);

  for (int t = 0; t < nsteps; ++t) {
    const int cur = t & 1;
    if (t + 1 < nsteps)
      asm volatile("s_waitcnt vmcnt(4)" ::: "memory");
    else
      asm volatile("s_waitcnt vmcnt(0)" ::: "memory");
    __builtin_amdgcn_s_barrier();
    __builtin_amdgcn_sched_barrier(0);

    bf16x8 af[4], bfr[4];
#pragma unroll
    for (int q = 0; q < 4; ++q)
      af[q] = *(const bf16x8*)(&As[cur][0] + (wm + q * 16 + lr) * 32 + lg * 8);
#pragma unroll
    for (int q = 0; q < 4; ++q)
      bfr[q] = *(const bf16x8*)(&Bs[cur][0] + (wn + q * 16 + lr) * 32 + lg * 8);
#pragma unroll
    for (int mt = 0; mt < 4; ++mt)
#pragma unroll
      for (int nt = 0; nt < 4; ++nt)
        acc[mt][nt] = __builtin_amdgcn_mfma_f32_16x16x32_bf16(af[mt], bfr[nt],
                                                              acc[mt][nt], 0, 0, 0);
    __builtin_amdgcn_s_barrier();
    __builtin_amdgcn_sched_barrier(0);
    if (t + 2 < nsteps) stage(cur, (t + 2) << 5);
  }

#pragma unroll
  for (int mt = 0; mt < 4; ++mt) {
#pragma unroll
    for (int nt = 0; nt < 4; ++nt) {
      int col = n0 + wn + nt * 16 + lr;
      int row0 = m0 + wm + mt * 16 + lg * 4;
      if constexpr (MODE == 0) {
#pragma unroll
        for (int r = 0; r < 4; ++r)
          ((bf16_t*)Cv)[(int64_t)(row0 + r) * Nc + col] =
              (bf16_t)(acc[mt][nt][r] * scale);
      } else if constexpr (MODE == 1) {
#pragma unroll
        for (int r = 0; r < 4; ++r)
          ((float*)Cv)[(int64_t)(row0 + r) * Nc + col] = acc[mt][nt][r] + bias[col];
      } else {
        if (col < 1024) {
#pragma unroll
          for (int r = 0; r < 4; ++r)
            ((bf16_t*)Cv)[(int64_t)(row0 + r) * 1024 + col] = (bf16_t)acc[mt][nt][r];
        } else {
          int hh = (col - 1024) >> 6, dd = col & 63;
          int bb = row0 >> 12, jj = row0 & (Jx - 1);
          bf16x4 ov;
#pragma unroll
          for (int r = 0; r < 4; ++r)
            ov[r] = (bf16_t)(acc[mt][nt][r] * gate[row0 + r]);
          *(bf16x4*)(VT + (((int64_t)(bb * Hx + hh) * HDx + dd) << 12) + jj) = ov;
        }
      }
    }
  }
}

// ---------------- flash attention: K in registers, V in LDS ----------------
// 1024 blocks: bits[3:0]=qi, [7:4]=h, [8]=chunk, [9]=b. 4 waves x 32 q-rows.
// K-fragments loaded straight from global (L2) into regs — LDS holds V only
// (halves LDS-pipe traffic, which was the saturated resource).
__launch_bounds__(256)
__global__ void k_attn(const bf16_t* __restrict__ Q, const bf16_t* __restrict__ Kbuf,
                       const bf16_t* __restrict__ VT, bf16_t* __restrict__ Opart,
                       float2* __restrict__ ML) {
  __shared__ bf16_t Vs[2][64 * 64];   // V^T: byte = d*128 + ((chunk ^ (d&7))*16)

  const int tid = threadIdx.x;
  const int w = tid >> 6, l = tid & 63;
  const int ql = l & 31, hi = l >> 5;

  const int lin = blockIdx.x;
  const int qi0 = lin & 15, h = (lin >> 4) & 15;
  const int c = (lin >> 8) & 1, b = lin >> 9;
  const int qi = b ? (15 - qi0) : qi0;
  const int q0 = qi * 128;

  const bf16_t* Qb = Q + ((int64_t)b * Nx) * DIMx + h * HDx;
  const bf16_t* Kb = Kbuf + ((int64_t)b * Jx) * 1024 + h * HDx;
  const bf16_t* Vb = VT + ((int64_t)(b * Hx + h) * HDx << 12);

  const int qrow = q0 + w * 32 + ql;

  bf16x8 qf[4];
#pragma unroll
  for (int dt = 0; dt < 4; ++dt)
    qf[dt] = *(const bf16x8*)(Qb + (int64_t)qrow * DIMx + dt * 16 + hi * 8);
  asm volatile("s_waitcnt vmcnt(0)" ::: "memory");  // qf resident; clean vmcnt

  int voff[2][4];
#pragma unroll
  for (int db = 0; db < 2; ++db)
#pragma unroll
    for (int jt = 0; jt < 4; ++jt)
      voff[db][jt] = (db * 32 + ql) * 128 + (((jt * 2 + hi) * 16) ^ ((ql & 7) * 16));

  bf16x8 onesv;
#pragma unroll
  for (int i = 0; i < 8; ++i) onesv[i] = (bf16_t)1.0f;

  f32x16 o[2] = {};
  f32x16 ol = {};
  float mrun = 8.0f;

  const int srow8 = l >> 3;
  const int swcol = ((l & 7) ^ srow8) * 8;
  const int jstart = c * 2048;                // fixed split (R8): even tiles both chunks
  const int jend = c ? ((Jx < q0 + 128 + MEMx) ? Jx : (q0 + 128 + MEMx)) : 2048;
  const int nt_tiles = (jend - jstart) >> 6;  // chunk0: 32, chunk1: 2+2*qi (>=2)
  const f32x16 z16 = {};

  const bf16_t* vsrc0 = Vb + (int64_t)(w * 16 + srow8) * Jx + swcol;

  auto stageV = [&](int bufi, int j0) {
    bf16_t* vd = &Vs[bufi][0] + w * 1024;
    const bf16_t* vs = vsrc0 + j0;
    gload_lds16(vs, vd);
    gload_lds16(vs + 8 * Jx, vd + 512);
  };

  // K-fragment pointers: lane (ql,hi) reads K[j0+jb*32+ql][dt*16+hi*8 ..+8)
  const bf16_t* kp0 = Kb + (int64_t)(jstart + ql) * 1024 + hi * 8;
  const bf16_t* kp1 = kp0 + 32 * 1024;

  bf16x8 kf[2][4];
  stageV(0, jstart);
  stageV(1, jstart + 64);
#pragma unroll
  for (int dt = 0; dt < 4; ++dt) {
    kf[0][dt] = *(const bf16x8*)(kp0 + dt * 16);
    kf[1][dt] = *(const bf16x8*)(kp1 + dt * 16);
  }

  for (int t = 0; t < nt_tiles; ++t) {
    const int cur = t & 1;
    const int j0 = jstart + (t << 6);
    if (t + 1 < nt_tiles)
      asm volatile("s_waitcnt vmcnt(2)" ::: "memory");   // V(t) + kf(t) landed
    else
      asm volatile("s_waitcnt vmcnt(0)" ::: "memory");
    __builtin_amdgcn_s_barrier();
    __builtin_amdgcn_sched_barrier(0);

    const char* VsC = (const char*)&Vs[cur][0];

    // S^T = K · Q^T  (K operands from registers)
    f32x16 s[2];
    __builtin_amdgcn_s_setprio(1);
#pragma unroll
    for (int jb = 0; jb < 2; ++jb) {
      f32x16 acc = z16;
#pragma unroll
      for (int dt = 0; dt < 4; ++dt)
        acc = __builtin_amdgcn_mfma_f32_32x32x16_bf16(kf[jb][dt], qf[dt], acc, 0, 0, 0);
      s[jb] = acc;
    }
    __builtin_amdgcn_s_setprio(0);

    // prefetch next tile's K fragments (regs already consumed by the MFMAs)
    if (t + 1 < nt_tiles) {
      kp0 += 64 * 1024;
      kp1 += 64 * 1024;
#pragma unroll
      for (int dt = 0; dt < 4; ++dt) {
        kf[0][dt] = *(const bf16x8*)(kp0 + dt * 16);
        kf[1][dt] = *(const bf16x8*)(kp1 + dt * 16);
      }
    }

    if (j0 + 63 > q0 + MEMx) {   // self-disables for chunk 0
#pragma unroll
      for (int jb = 0; jb < 2; ++jb)
#pragma unroll
        for (int r = 0; r < 16; ++r) {
          int j = j0 + jb * 32 + (r & 3) + (r >> 2) * 8 + hi * 4;
          if (j > qrow + MEMx) s[jb][r] = -1e30f;
        }
    }

    // tile max (v_max3 tree) + 1 shfl; defer-max rescale
    float t12[12];
#pragma unroll
    for (int i = 0; i < 10; ++i)
      t12[i] = fmax3(s[(3 * i) >> 4][(3 * i) & 15], s[(3 * i + 1) >> 4][(3 * i + 1) & 15],
                     s[(3 * i + 2) >> 4][(3 * i + 2) & 15]);
    t12[10] = s[1][14];
    t12[11] = s[1][15];
    float t4[4];
#pragma unroll
    for (int i = 0; i < 4; ++i) t4[i] = fmax3(t12[3 * i], t12[3 * i + 1], t12[3 * i + 2]);
    float tm = fmaxf(fmax3(t4[0], t4[1], t4[2]), t4[3]);
    tm = fmaxf(tm, __shfl_xor(tm, 32));

    if (!__all(tm <= mrun + 8.f)) {
      float mnew = fmaxf(mrun, tm);
      float al = exp2f(mrun - mnew);
      mrun = mnew;
#pragma unroll
      for (int r = 0; r < 16; ++r) ol[r] *= al;
#pragma unroll
      for (int db = 0; db < 2; ++db)
#pragma unroll
        for (int r = 0; r < 16; ++r) o[db][r] *= al;
    }

#pragma unroll
    for (int jb = 0; jb < 2; ++jb)
#pragma unroll
      for (int r = 0; r < 16; ++r) s[jb][r] = exp2f(s[jb][r] - mrun);

    // P^T -> B-operand frags (cvt_pk + permlane32 half-swaps)
    bf16x8 pfrag[4];
#pragma unroll
    for (int jb = 0; jb < 2; ++jb) {
      int pw[8];
#pragma unroll
      for (int g = 0; g < 8; ++g) pw[g] = pk2(s[jb][2 * g], s[jb][2 * g + 1]);
      pl32swap(pw[0], pw[2]);
      pl32swap(pw[1], pw[3]);
      pl32swap(pw[4], pw[6]);
      pl32swap(pw[5], pw[7]);
      i32x4 f0 = {pw[0], pw[1], pw[2], pw[3]};
      i32x4 f1 = {pw[4], pw[5], pw[6], pw[7]};
      pfrag[jb * 2] = __builtin_bit_cast(bf16x8, f0);
      pfrag[jb * 2 + 1] = __builtin_bit_cast(bf16x8, f1);
    }

    // O^T += V^T · P^T ; l += ones · P^T (matrix pipe)
    __builtin_amdgcn_s_setprio(1);
#pragma unroll
    for (int jt = 0; jt < 4; ++jt) {
      bf16x8 vf0 = *(const bf16x8*)(VsC + voff[0][jt]);
      o[0] = __builtin_amdgcn_mfma_f32_32x32x16_bf16(vf0, pfrag[jt], o[0], 0, 0, 0);
      bf16x8 vf1 = *(const bf16x8*)(VsC + voff[1][jt]);
      o[1] = __builtin_amdgcn_mfma_f32_32x32x16_bf16(vf1, pfrag[jt], o[1], 0, 0, 0);
      ol = __builtin_amdgcn_mfma_f32_32x32x16_bf16(onesv, pfrag[jt], ol, 0, 0, 0);
    }
    __builtin_amdgcn_s_setprio(0);

    __builtin_amdgcn_s_barrier();
    __builtin_amdgcn_sched_barrier(0);
    if (t + 2 < nt_tiles) stageV(cur, jstart + ((t + 2) << 6));
  }

  // epilogue: un-normalized O^T + (m,l); k_combine normalizes
  bf16_t* op = Opart + (int64_t)c * (Bx * Nx * DIMx) +
               (int64_t)(b * Nx + qrow) * DIMx + h * HDx;
#pragma unroll
  for (int db = 0; db < 2; ++db)
#pragma unroll
    for (int g = 0; g < 4; ++g) {
      bf16x4 ov;
#pragma unroll
      for (int r = 0; r < 4; ++r) ov[r] = (bf16_t)o[db][g * 4 + r];
      *(bf16x4*)(op + db * 32 + g * 8 + hi * 4) = ov;
    }
  if (hi == 0)
    ML[((int64_t)(c * Bx + b) * Hx + h) * Nx + qrow] = make_float2(mrun, ol[0]);
}

// ---------------- combine: merge the two J-chunks ----------------
__global__ void k_combine(const bf16_t* __restrict__ Op, const float2* __restrict__ ML,
                          bf16_t* __restrict__ Ho) {
  const int64_t CH = (int64_t)Bx * Nx * DIMx;
  int i = blockIdx.x * blockDim.x + threadIdx.x;
  const int total = (int)(CH >> 3);
  if (i >= total) return;
  int64_t off = (int64_t)i * 8;
  int bqh = (int)(off >> 6);
  int h = bqh & 15;
  int bq = bqh >> 4;
  int b = bq >> 11, q = bq & (Nx - 1);
  float2 ml0 = ML[((int64_t)b * Hx + h) * Nx + q];
  float2 ml1 = ML[((int64_t)(Bx + b) * Hx + h) * Nx + q];
  float M = fmaxf(ml0.x, ml1.x);
  float a0 = exp2f(ml0.x - M), a1 = exp2f(ml1.x - M);
  float inv = 1.f / (a0 * ml0.y + a1 * ml1.y);
  a0 *= inv;
  a1 *= inv;
  bf16x8 v0 = *(const bf16x8*)(Op + off);
  bf16x8 v1 = *(const bf16x8*)(Op + CH + off);
  bf16x8 outv;
#pragma unroll
  for (int r = 0; r < 8; ++r)
    outv[r] = (bf16_t)(a0 * (float)v0[r] + a1 * (float)v1[r]);
  *(bf16x8*)(Ho + off) = outv;
}

// ---------------- launcher ----------------
extern "C" void kernel_launch(void* const* d_in, const int* in_sizes, int n_in,
                              void* d_out, int out_size, void* d_ws, size_t ws_size,
                              hipStream_t stream) {
  const float* x    = (const float*)d_in[0];
  const float* mem  = (const float*)d_in[1];
  const float* expm = (const float*)d_in[2];
  const float* Wq   = (const float*)d_in[3];
  const float* Wkv  = (const float*)d_in[4];
  const float* Wo   = (const float*)d_in[5];
  const float* bo   = (const float*)d_in[6];
  float* out = (float*)d_out;

  bf16_t* p = (bf16_t*)d_ws;
  bf16_t* xb   = p; p += (size_t)Bx * Nx * DIMx;
  bf16_t* ctxb = p; p += (size_t)Bx * Jx * DIMx;
  bf16_t* WqT  = p; p += (size_t)DIMx * DIMx;
  bf16_t* WkvT = p; p += (size_t)DIMx * 2 * DIMx;
  bf16_t* WoT  = p; p += (size_t)DIMx * DIMx;
  bf16_t* Qb   = p; p += (size_t)Bx * Nx * DIMx;
  bf16_t* KVb  = p; p += (size_t)Bx * Jx * 2 * DIMx;
  bf16_t* Ho   = p; p += (size_t)Bx * Nx * DIMx;

  bf16_t* Kbuf = KVb;
  bf16_t* VT   = KVb + (size_t)Bx * Jx * 1024;
  bf16_t* Opart = ctxb;
  float2* ML    = (float2*)xb;

  k_build8<<<2048, 256, 0, stream>>>(x, mem, xb, ctxb);
  k_transpose_tiled<<<dim3(32, 32), 256, 0, stream>>>(Wq, WqT, DIMx, DIMx);
  k_transpose_tiled<<<dim3(64, 32), 256, 0, stream>>>(Wkv, WkvT, DIMx, 2 * DIMx);
  k_transpose_tiled<<<dim3(32, 32), 256, 0, stream>>>(Wo, WoT, DIMx, DIMx);

  const float qscale = 0.125f * 1.4426950408889634f;
  k_gemm_bt<0><<<dim3(1024 / 128, 4096 / 128), 256, 0, stream>>>(
      xb, WqT, Qb, nullptr, nullptr, nullptr, qscale, Bx * Nx, DIMx, DIMx);
  k_gemm_bt<2><<<dim3(2048 / 128, 8192 / 128), 256, 0, stream>>>(
      ctxb, WkvT, Kbuf, nullptr, expm, VT, 1.0f, Bx * Jx, 2 * DIMx, DIMx);

  k_attn<<<1024, 256, 0, stream>>>(Qb, Kbuf, VT, Opart, ML);
  k_combine<<<(Bx * Nx * DIMx / 8 + 255) / 256, 256, 0, stream>>>(Opart, ML, Ho);

  k_gemm_bt<1><<<dim3(1024 / 128, 4096 / 128), 256, 0, stream>>>(
      Ho, WoT, out, bo, nullptr, nullptr, 1.0f, Bx * Nx, DIMx, DIMx);
}

// Round 12
// 247.788 us; speedup vs baseline: 1.1314x; 1.1314x over previous
//
#include <hip/hip_runtime.h>
#include <cstdint>

typedef __bf16 bf16_t;
typedef __attribute__((ext_vector_type(2))) __bf16 bf16x2;
typedef __attribute__((ext_vector_type(4))) __bf16 bf16x4;
typedef __attribute__((ext_vector_type(8))) __bf16 bf16x8;
typedef __attribute__((ext_vector_type(4))) float f32x4;
typedef __attribute__((ext_vector_type(16))) float f32x16;
typedef __attribute__((ext_vector_type(4))) int i32x4;

constexpr int Bx = 2, Nx = 2048, MEMx = 2048, Jx = 4096, DIMx = 1024, Hx = 16, HDx = 64;

__device__ __forceinline__ void gload_lds16(const bf16_t* g, bf16_t* lds) {
  __builtin_amdgcn_global_load_lds(
      (const __attribute__((address_space(1))) unsigned int*)g,
      (__attribute__((address_space(3))) unsigned int*)lds, 16, 0, 0);
}

__device__ __forceinline__ int pk2(float a, float b) {
  bf16x2 t;
  t[0] = (bf16_t)a;
  t[1] = (bf16_t)b;
  return __builtin_bit_cast(int, t);
}

__device__ __forceinline__ void pl32swap(int& a, int& b) {
  asm volatile("v_permlane32_swap_b32 %0, %1" : "+v"(a), "+v"(b));
}

__device__ __forceinline__ float fmax3(float a, float b, float c) {
  float d;
  asm("v_max3_f32 %0, %1, %2, %3" : "=v"(d) : "v"(a), "v"(b), "v"(c));
  return d;
}

// ---------------- convert / pack (vectorized) ----------------
__global__ void k_build8(const float* __restrict__ x, const float* __restrict__ mem,
                         bf16_t* __restrict__ xb, bf16_t* __restrict__ ctxb) {
  const int XT8 = (Bx * Nx * DIMx) >> 3;
  const int CT8 = (Bx * Jx * DIMx) >> 3;
  for (int i = blockIdx.x * blockDim.x + threadIdx.x; i < XT8 + CT8;
       i += gridDim.x * blockDim.x) {
    const float* src;
    bf16_t* dst;
    if (i < XT8) {
      src = x + ((int64_t)i << 3);
      dst = xb + ((int64_t)i << 3);
    } else {
      int64_t c = (int64_t)(i - XT8) << 3;
      int bb = (int)(c >> 22);
      int rr = (int)(c & ((1 << 22) - 1));
      int j = rr >> 10, d = rr & 1023;
      src = (j < MEMx) ? mem + (((int64_t)(bb * MEMx + j)) << 10) + d
                       : x + (((int64_t)(bb * Nx + (j - MEMx))) << 10) + d;
      dst = ctxb + c;
    }
    float4 a = *(const float4*)src;
    float4 b = *(const float4*)(src + 4);
    bf16x8 v;
    v[0] = (bf16_t)a.x; v[1] = (bf16_t)a.y; v[2] = (bf16_t)a.z; v[3] = (bf16_t)a.w;
    v[4] = (bf16_t)b.x; v[5] = (bf16_t)b.y; v[6] = (bf16_t)b.z; v[7] = (bf16_t)b.w;
    *(bf16x8*)dst = v;
  }
}

__global__ void k_transpose_tiled(const float* __restrict__ W, bf16_t* __restrict__ WT,
                                  int K, int Nc) {
  __shared__ bf16_t t[32][33];
  const int tx = threadIdx.x & 31, ty = threadIdx.x >> 5;
  const int n0 = blockIdx.x * 32, k0 = blockIdx.y * 32;
#pragma unroll
  for (int r = 0; r < 4; ++r)
    t[ty + 8 * r][tx] = (bf16_t)W[(int64_t)(k0 + ty + 8 * r) * Nc + n0 + tx];
  __syncthreads();
#pragma unroll
  for (int r = 0; r < 4; ++r)
    WT[(int64_t)(n0 + ty + 8 * r) * K + k0 + tx] = t[tx][ty + 8 * r];
}

// ---------------- GEMM (depth-2 counted-vmcnt) ----------------
template <int MODE>
__launch_bounds__(256)
__global__ void k_gemm_bt(const bf16_t* __restrict__ A, const bf16_t* __restrict__ BT,
                          void* __restrict__ Cv, const float* __restrict__ bias,
                          const float* __restrict__ gate, bf16_t* __restrict__ VT,
                          float scale, int M, int Nc, int K) {
  __shared__ bf16_t As[2][128 * 32];
  __shared__ bf16_t Bs[2][128 * 32];
  const int tid = threadIdx.x;
  const int w = tid >> 6, l = tid & 63;
  const int lr = l & 15, lg = l >> 4;
  const int m0 = blockIdx.y * 128, n0 = blockIdx.x * 128;
  const int wm = (w >> 1) * 64, wn = (w & 1) * 64;

  const int srow = w * 16 + (l >> 2);
  const int scol = (l & 3) * 8;
  const bf16_t* ga0 = A + (int64_t)(m0 + srow) * K + scol;
  const bf16_t* gb0 = BT + (int64_t)(n0 + srow) * K + scol;

  auto stage = [&](int bufi, int k0) {
    bf16_t* lA = &As[bufi][0] + w * 512;
    bf16_t* lB = &Bs[bufi][0] + w * 512;
    gload_lds16(ga0 + k0, lA);
    gload_lds16(ga0 + (int64_t)64 * K + k0, lA + 2048);
    gload_lds16(gb0 + k0, lB);
    gload_lds16(gb0 + (int64_t)64 * K + k0, lB + 2048);
  };

  f32x4 acc[4][4] = {};

  const int nsteps = K >> 5;
  stage(0, 0);
  stage(1, 32);

  for (int t = 0; t < nsteps; ++t) {
    const int cur = t & 1;
    if (t + 1 < nsteps)
      asm volatile("s_waitcnt vmcnt(4)" ::: "memory");
    else
      asm volatile("s_waitcnt vmcnt(0)" ::: "memory");
    __builtin_amdgcn_s_barrier();
    __builtin_amdgcn_sched_barrier(0);

    bf16x8 af[4], bfr[4];
#pragma unroll
    for (int q = 0; q < 4; ++q)
      af[q] = *(const bf16x8*)(&As[cur][0] + (wm + q * 16 + lr) * 32 + lg * 8);
#pragma unroll
    for (int q = 0; q < 4; ++q)
      bfr[q] = *(const bf16x8*)(&Bs[cur][0] + (wn + q * 16 + lr) * 32 + lg * 8);
#pragma unroll
    for (int mt = 0; mt < 4; ++mt)
#pragma unroll
      for (int nt = 0; nt < 4; ++nt)
        acc[mt][nt] = __builtin_amdgcn_mfma_f32_16x16x32_bf16(af[mt], bfr[nt],
                                                              acc[mt][nt], 0, 0, 0);
    __builtin_amdgcn_s_barrier();
    __builtin_amdgcn_sched_barrier(0);
    if (t + 2 < nsteps) stage(cur, (t + 2) << 5);
  }

#pragma unroll
  for (int mt = 0; mt < 4; ++mt) {
#pragma unroll
    for (int nt = 0; nt < 4; ++nt) {
      int col = n0 + wn + nt * 16 + lr;
      int row0 = m0 + wm + mt * 16 + lg * 4;
      if constexpr (MODE == 0) {
#pragma unroll
        for (int r = 0; r < 4; ++r)
          ((bf16_t*)Cv)[(int64_t)(row0 + r) * Nc + col] =
              (bf16_t)(acc[mt][nt][r] * scale);
      } else if constexpr (MODE == 1) {
#pragma unroll
        for (int r = 0; r < 4; ++r)
          ((float*)Cv)[(int64_t)(row0 + r) * Nc + col] = acc[mt][nt][r] + bias[col];
      } else {
        if (col < 1024) {
#pragma unroll
          for (int r = 0; r < 4; ++r)
            ((bf16_t*)Cv)[(int64_t)(row0 + r) * 1024 + col] = (bf16_t)acc[mt][nt][r];
        } else {
          int hh = (col - 1024) >> 6, dd = col & 63;
          int bb = row0 >> 12, jj = row0 & (Jx - 1);
          bf16x4 ov;
#pragma unroll
          for (int r = 0; r < 4; ++r)
            ov[r] = (bf16_t)(acc[mt][nt][r] * gate[row0 + r]);
          *(bf16x4*)(VT + (((int64_t)(bb * Hx + hh) * HDx + dd) << 12) + jj) = ov;
        }
      }
    }
  }
}

// ---------------- flash attention: T15 2-deep pipeline, 1 barrier/tile -------
// 1024 blocks: bits[3:0]=qi, [7:4]=h, [8]=chunk, [9]=b. 4 waves x 32 q-rows.
// Tri-buffered K/V LDS; per iter: vmcnt(2), barrier, stage(t+2), QK(t+1),
// softmax(t), PV(t). QK-next MFMA latency hides under softmax VALU.
__launch_bounds__(256, 2)
__global__ void k_attn(const bf16_t* __restrict__ Q, const bf16_t* __restrict__ Kbuf,
                       const bf16_t* __restrict__ VT, bf16_t* __restrict__ Opart,
                       float2* __restrict__ ML) {
  __shared__ bf16_t Ks[3][64 * 64];   // byte = j*128 + ((chunk ^ (j&7))*16)
  __shared__ bf16_t Vs[3][64 * 64];   // V^T: byte = d*128 + ((chunk ^ (d&7))*16)

  const int tid = threadIdx.x;
  const int w = tid >> 6, l = tid & 63;
  const int ql = l & 31, hi = l >> 5;

  const int lin = blockIdx.x;
  const int qi0 = lin & 15, h = (lin >> 4) & 15;
  const int c = (lin >> 8) & 1, b = lin >> 9;
  const int qi = b ? (15 - qi0) : qi0;
  const int q0 = qi * 128;

  const bf16_t* Qb = Q + ((int64_t)b * Nx) * DIMx + h * HDx;
  const bf16_t* Kb = Kbuf + ((int64_t)b * Jx) * 1024 + h * HDx;
  const bf16_t* Vb = VT + ((int64_t)(b * Hx + h) * HDx << 12);

  const int qrow = q0 + w * 32 + ql;

  bf16x8 qf[4];
#pragma unroll
  for (int dt = 0; dt < 4; ++dt)
    qf[dt] = *(const bf16x8*)(Qb + (int64_t)qrow * DIMx + dt * 16 + hi * 8);
  asm volatile("s_waitcnt vmcnt(0)" ::: "memory");  // qf resident; clean vmcnt

  int koff[2][4], voff[2][4];
#pragma unroll
  for (int jb = 0; jb < 2; ++jb)
#pragma unroll
    for (int dt = 0; dt < 4; ++dt)
      koff[jb][dt] = (jb * 32 + ql) * 128 + (((dt * 2 + hi) * 16) ^ ((ql & 7) * 16));
#pragma unroll
  for (int db = 0; db < 2; ++db)
#pragma unroll
    for (int jt = 0; jt < 4; ++jt)
      voff[db][jt] = (db * 32 + ql) * 128 + (((jt * 2 + hi) * 16) ^ ((ql & 7) * 16));

  bf16x8 onesv;
#pragma unroll
  for (int i = 0; i < 8; ++i) onesv[i] = (bf16_t)1.0f;

  f32x16 o[2] = {};
  f32x16 ol = {};
  float mrun = 8.0f;

  const int srow8 = l >> 3;
  const int swcol = ((l & 7) ^ srow8) * 8;
  const int jstart = c * 2048;   // fixed split: chunk0 32 tiles, chunk1 2+2*qi
  const int jend = c ? ((Jx < q0 + 128 + MEMx) ? Jx : (q0 + 128 + MEMx)) : 2048;
  const int nt_tiles = (jend - jstart) >> 6;   // always even, >= 2
  const f32x16 z16 = {};

  const bf16_t* ksrc0 = Kb + (int64_t)(w * 16 + srow8) * 1024 + swcol;
  const bf16_t* vsrc0 = Vb + (int64_t)(w * 16 + srow8) * Jx + swcol;
  const char* KsBase = (const char*)&Ks[0][0];
  const char* VsBase = (const char*)&Vs[0][0];

  // issue order K,K,V,V — the counted-vmcnt drain analysis relies on it
  auto stageKV = [&](int bi, int j0) {
    bf16_t* kd = &Ks[bi][0] + w * 1024;
    const bf16_t* ks = ksrc0 + (int64_t)j0 * 1024;
    gload_lds16(ks, kd);
    gload_lds16(ks + 8 * 1024, kd + 512);
    bf16_t* vd = &Vs[bi][0] + w * 1024;
    const bf16_t* vs = vsrc0 + j0;
    gload_lds16(vs, vd);
    gload_lds16(vs + 8 * Jx, vd + 512);
  };

  f32x16 sA[2], sB[2];
  int ib = 0, inb = 1, ist = 2;   // t%3, (t+1)%3, (t+2)%3

  // prologue: stage tiles 0,1; QK(0) -> sA
  stageKV(0, jstart);
  stageKV(1, jstart + 64);
  asm volatile("s_waitcnt vmcnt(6)" ::: "memory");   // K(0) landed
  __builtin_amdgcn_s_barrier();
  __builtin_amdgcn_sched_barrier(0);
  {
    __builtin_amdgcn_s_setprio(1);
#pragma unroll
    for (int jb = 0; jb < 2; ++jb) {
      f32x16 acc = z16;
#pragma unroll
      for (int dt = 0; dt < 4; ++dt) {
        bf16x8 kf = *(const bf16x8*)(KsBase + koff[jb][dt]);
        acc = __builtin_amdgcn_mfma_f32_32x32x16_bf16(kf, qf[dt], acc, 0, 0, 0);
      }
      sA[jb] = acc;
    }
    __builtin_amdgcn_s_setprio(0);
  }

#define ATTN_BODY(SCUR, SNXT, T)                                                     \
  do {                                                                               \
    const int j0_ = jstart + ((T) << 6);                                             \
    if ((T) + 1 < nt_tiles)                                                          \
      asm volatile("s_waitcnt vmcnt(2)" ::: "memory");                               \
    else                                                                             \
      asm volatile("s_waitcnt vmcnt(0)" ::: "memory");                               \
    __builtin_amdgcn_s_barrier();                                                    \
    __builtin_amdgcn_sched_barrier(0);                                               \
    if ((T) + 2 < nt_tiles) stageKV(ist, jstart + (((T) + 2) << 6));                 \
    if ((T) + 1 < nt_tiles) {                                                        \
      const char* Kn_ = KsBase + inb * 8192;                                         \
      __builtin_amdgcn_s_setprio(1);                                                 \
      _Pragma("unroll") for (int jb = 0; jb < 2; ++jb) {                             \
        f32x16 acc_ = z16;                                                           \
        _Pragma("unroll") for (int dt = 0; dt < 4; ++dt) {                           \
          bf16x8 kf_ = *(const bf16x8*)(Kn_ + koff[jb][dt]);                         \
          acc_ = __builtin_amdgcn_mfma_f32_32x32x16_bf16(kf_, qf[dt], acc_, 0, 0, 0);\
        }                                                                            \
        SNXT[jb] = acc_;                                                             \
      }                                                                              \
      __builtin_amdgcn_s_setprio(0);                                                 \
      __builtin_amdgcn_sched_barrier(0);                                             \
    }                                                                                \
    if (j0_ + 63 > q0 + MEMx) {                                                      \
      _Pragma("unroll") for (int jb = 0; jb < 2; ++jb)                               \
      _Pragma("unroll") for (int r = 0; r < 16; ++r) {                               \
        int j_ = j0_ + jb * 32 + (r & 3) + (r >> 2) * 8 + hi * 4;                    \
        if (j_ > qrow + MEMx) SCUR[jb][r] = -1e30f;                                  \
      }                                                                              \
    }                                                                                \
    float t12_[12];                                                                  \
    _Pragma("unroll") for (int i = 0; i < 10; ++i)                                   \
        t12_[i] = fmax3(SCUR[(3 * i) >> 4][(3 * i) & 15],                            \
                        SCUR[(3 * i + 1) >> 4][(3 * i + 1) & 15],                    \
                        SCUR[(3 * i + 2) >> 4][(3 * i + 2) & 15]);                   \
    t12_[10] = SCUR[1][14];                                                          \
    t12_[11] = SCUR[1][15];                                                          \
    float t4_[4];                                                                    \
    _Pragma("unroll") for (int i = 0; i < 4; ++i)                                    \
        t4_[i] = fmax3(t12_[3 * i], t12_[3 * i + 1], t12_[3 * i + 2]);               \
    float tm_ = fmaxf(fmax3(t4_[0], t4_[1], t4_[2]), t4_[3]);                        \
    tm_ = fmaxf(tm_, __shfl_xor(tm_, 32));                                           \
    if (!__all(tm_ <= mrun + 8.f)) {                                                 \
      float mnew_ = fmaxf(mrun, tm_);                                                \
      float al_ = exp2f(mrun - mnew_);                                               \
      mrun = mnew_;                                                                  \
      _Pragma("unroll") for (int r = 0; r < 16; ++r) ol[r] *= al_;                   \
      _Pragma("unroll") for (int db = 0; db < 2; ++db)                               \
      _Pragma("unroll") for (int r = 0; r < 16; ++r) o[db][r] *= al_;                \
    }                                                                                \
    _Pragma("unroll") for (int jb = 0; jb < 2; ++jb)                                 \
    _Pragma("unroll") for (int r = 0; r < 16; ++r)                                   \
        SCUR[jb][r] = exp2f(SCUR[jb][r] - mrun);                                     \
    bf16x8 pfrag_[4];                                                                \
    _Pragma("unroll") for (int jb = 0; jb < 2; ++jb) {                               \
      int pw_[8];                                                                    \
      _Pragma("unroll") for (int g = 0; g < 8; ++g)                                  \
          pw_[g] = pk2(SCUR[jb][2 * g], SCUR[jb][2 * g + 1]);                        \
      pl32swap(pw_[0], pw_[2]);                                                      \
      pl32swap(pw_[1], pw_[3]);                                                      \
      pl32swap(pw_[4], pw_[6]);                                                      \
      pl32swap(pw_[5], pw_[7]);                                                      \
      i32x4 f0_ = {pw_[0], pw_[1], pw_[2], pw_[3]};                                  \
      i32x4 f1_ = {pw_[4], pw_[5], pw_[6], pw_[7]};                                  \
      pfrag_[jb * 2] = __builtin_bit_cast(bf16x8, f0_);                              \
      pfrag_[jb * 2 + 1] = __builtin_bit_cast(bf16x8, f1_);                          \
    }                                                                                \
    const char* Vc_ = VsBase + ib * 8192;                                            \
    __builtin_amdgcn_s_setprio(1);                                                   \
    _Pragma("unroll") for (int jt = 0; jt < 4; ++jt) {                               \
      bf16x8 vf0_ = *(const bf16x8*)(Vc_ + voff[0][jt]);                             \
      o[0] = __builtin_amdgcn_mfma_f32_32x32x16_bf16(vf0_, pfrag_[jt], o[0], 0, 0, 0);\
      bf16x8 vf1_ = *(const bf16x8*)(Vc_ + voff[1][jt]);                             \
      o[1] = __builtin_amdgcn_mfma_f32_32x32x16_bf16(vf1_, pfrag_[jt], o[1], 0, 0, 0);\
      ol = __builtin_amdgcn_mfma_f32_32x32x16_bf16(onesv, pfrag_[jt], ol, 0, 0, 0);  \
    }                                                                                \
    __builtin_amdgcn_s_setprio(0);                                                   \
    int tmp_ = ib; ib = inb; inb = ist; ist = tmp_;                                  \
  } while (0)

  for (int t = 0; t < nt_tiles; t += 2) {
    ATTN_BODY(sA, sB, t);
    ATTN_BODY(sB, sA, t + 1);
  }
#undef ATTN_BODY

  // epilogue: un-normalized O^T + (m,l); k_combine normalizes
  bf16_t* op = Opart + (int64_t)c * (Bx * Nx * DIMx) +
               (int64_t)(b * Nx + qrow) * DIMx + h * HDx;
#pragma unroll
  for (int db = 0; db < 2; ++db)
#pragma unroll
    for (int g = 0; g < 4; ++g) {
      bf16x4 ov;
#pragma unroll
      for (int r = 0; r < 4; ++r) ov[r] = (bf16_t)o[db][g * 4 + r];
      *(bf16x4*)(op + db * 32 + g * 8 + hi * 4) = ov;
    }
  if (hi == 0)
    ML[((int64_t)(c * Bx + b) * Hx + h) * Nx + qrow] = make_float2(mrun, ol[0]);
}

// ---------------- combine: merge the two J-chunks ----------------
__global__ void k_combine(const bf16_t* __restrict__ Op, const float2* __restrict__ ML,
                          bf16_t* __restrict__ Ho) {
  const int64_t CH = (int64_t)Bx * Nx * DIMx;
  int i = blockIdx.x * blockDim.x + threadIdx.x;
  const int total = (int)(CH >> 3);
  if (i >= total) return;
  int64_t off = (int64_t)i * 8;
  int bqh = (int)(off >> 6);
  int h = bqh & 15;
  int bq = bqh >> 4;
  int b = bq >> 11, q = bq & (Nx - 1);
  float2 ml0 = ML[((int64_t)b * Hx + h) * Nx + q];
  float2 ml1 = ML[((int64_t)(Bx + b) * Hx + h) * Nx + q];
  float M = fmaxf(ml0.x, ml1.x);
  float a0 = exp2f(ml0.x - M), a1 = exp2f(ml1.x - M);
  float inv = 1.f / (a0 * ml0.y + a1 * ml1.y);
  a0 *= inv;
  a1 *= inv;
  bf16x8 v0 = *(const bf16x8*)(Op + off);
  bf16x8 v1 = *(const bf16x8*)(Op + CH + off);
  bf16x8 outv;
#pragma unroll
  for (int r = 0; r < 8; ++r)
    outv[r] = (bf16_t)(a0 * (float)v0[r] + a1 * (float)v1[r]);
  *(bf16x8*)(Ho + off) = outv;
}

// ---------------- launcher ----------------
extern "C" void kernel_launch(void* const* d_in, const int* in_sizes, int n_in,
                              void* d_out, int out_size, void* d_ws, size_t ws_size,
                              hipStream_t stream) {
  const float* x    = (const float*)d_in[0];
  const float* mem  = (const float*)d_in[1];
  const float* expm = (const float*)d_in[2];
  const float* Wq   = (const float*)d_in[3];
  const float* Wkv  = (const float*)d_in[4];
  const float* Wo   = (const float*)d_in[5];
  const float* bo   = (const float*)d_in[6];
  float* out = (float*)d_out;

  bf16_t* p = (bf16_t*)d_ws;
  bf16_t* xb   = p; p += (size_t)Bx * Nx * DIMx;
  bf16_t* ctxb = p; p += (size_t)Bx * Jx * DIMx;
  bf16_t* WqT  = p; p += (size_t)DIMx * DIMx;
  bf16_t* WkvT = p; p += (size_t)DIMx * 2 * DIMx;
  bf16_t* WoT  = p; p += (size_t)DIMx * DIMx;
  bf16_t* Qb   = p; p += (size_t)Bx * Nx * DIMx;
  bf16_t* KVb  = p; p += (size_t)Bx * Jx * 2 * DIMx;
  bf16_t* Ho   = p; p += (size_t)Bx * Nx * DIMx;

  bf16_t* Kbuf = KVb;
  bf16_t* VT   = KVb + (size_t)Bx * Jx * 1024;
  bf16_t* Opart = ctxb;
  float2* ML    = (float2*)xb;

  k_build8<<<2048, 256, 0, stream>>>(x, mem, xb, ctxb);
  k_transpose_tiled<<<dim3(32, 32), 256, 0, stream>>>(Wq, WqT, DIMx, DIMx);
  k_transpose_tiled<<<dim3(64, 32), 256, 0, stream>>>(Wkv, WkvT, DIMx, 2 * DIMx);
  k_transpose_tiled<<<dim3(32, 32), 256, 0, stream>>>(Wo, WoT, DIMx, DIMx);

  const float qscale = 0.125f * 1.4426950408889634f;
  k_gemm_bt<0><<<dim3(1024 / 128, 4096 / 128), 256, 0, stream>>>(
      xb, WqT, Qb, nullptr, nullptr, nullptr, qscale, Bx * Nx, DIMx, DIMx);
  k_gemm_bt<2><<<dim3(2048 / 128, 8192 / 128), 256, 0, stream>>>(
      ctxb, WkvT, Kbuf, nullptr, expm, VT, 1.0f, Bx * Jx, 2 * DIMx, DIMx);

  k_attn<<<1024, 256, 0, stream>>>(Qb, Kbuf, VT, Opart, ML);
  k_combine<<<(Bx * Nx * DIMx / 8 + 255) / 256, 256, 0, stream>>>(Opart, ML, Ho);

  k_gemm_bt<1><<<dim3(1024 / 128, 4096 / 128), 256, 0, stream>>>(
      Ho, WoT, out, bo, nullptr, nullptr, 1.0f, Bx * Nx, DIMx, DIMx);
}